// Round 11
// baseline (411.485 us; speedup 1.0000x reference)
//
#include <hip/hip_runtime.h>
#include <hip/hip_bf16.h>

using bf16 = __hip_bfloat16;

typedef __attribute__((ext_vector_type(8))) short short8;
typedef __attribute__((ext_vector_type(4))) float f32x4;

constexpr int Bb = 32, Dd = 256, HWw = 4096, Kk = 256, Ff = 2048;
constexpr float TEMP_INV = 1.0f / 0.07f;
constexpr float EPSf = 1e-6f;
constexpr float NORM_EPSf = 1e-12f;
constexpr float LN_EPSf = 1e-5f;
constexpr size_t PKD = (size_t)Bb * Kk * Dd;   // one t2 partial (2M floats = 8 MB)

static __device__ __forceinline__ float b2f(bf16 v) { return __bfloat162float(v); }
static __device__ __forceinline__ bf16 f2b(float v) { return __float2bfloat16(v); }

// Fragment-order conventions (16x16x32 MFMA, K-step 32):
//   element (row, k): set = k>>5, q2 = (k>>3)&3, j = k&7
//   256-row group (tnbf, attn_bf, xb_bf): fi = (row>>4)*64 + q2*16 + (row&15); 1024 frags/step
//   64-row group (tbf/w1bf/w2bf):         fi = ((row&63)>>4)*64 + q2*16 + (row&15); 256 frags/step
//   32-row group (k_ffn rp tile):         fi = ((row&31)>>4)*64 + q2*16 + (row&15); 128 frags/set
// Reader identity: addr = set_base + (mtile_local*64 + lane)*8  (lane = q2*16 + row&15)
// LDS repack swizzle (bank-spread, involution): fi_sw = fi ^ ((fi>>3)&3)
//
// Config provenance (measured):
//   k_dots: THIS ROUND — hw-window 64->32 (acc[4][2]=32 AGPR) to break the 3-waves/SIMD reg cap;
//     bounds(256,4); step-parity staging keeps d-pair packing. R10 config measured 91us @27% occ.
//   k_gemm2: R8 hs-4 K-split partials, grid 2048.
//   k_ffn: fused ffn1+ffn2 (R10: correct; traffic saving ~neutral -> mid-pipe is latency-bound).

// ---------------- k_tn: tnbf = l2norm(tgt) bf16, 256-row-group fragment order ----------------
__global__ __launch_bounds__(64) void k_tn(const float* __restrict__ tgt,
                                           bf16* __restrict__ tnbf) {
  int row = blockIdx.x;            // b*256 + slot
  int b = row >> 8, slot = row & 255;
  int lane = threadIdx.x;
  const float* src = tgt + (size_t)row * Dd + lane * 4;
  float v[4];
#pragma unroll
  for (int u = 0; u < 4; u++) v[u] = src[u];
  float ss = v[0] * v[0] + v[1] * v[1] + v[2] * v[2] + v[3] * v[3];
#pragma unroll
  for (int m = 32; m >= 1; m >>= 1) ss += __shfl_xor(ss, m, 64);
  float inv = 1.0f / fmaxf(sqrtf(ss), NORM_EPSf);
  bf16 o[4] __attribute__((aligned(8)));
#pragma unroll
  for (int u = 0; u < 4; u++) o[u] = f2b(v[u] * inv);
  int s = lane >> 3;
  int q2 = (lane >> 1) & 3;
  int jh = (lane & 1) * 4;
  size_t fi = (size_t)((slot >> 4) * 64 + q2 * 16 + (slot & 15));
  *(float2*)(tnbf + ((size_t)(b * 8 + s) * 1024 + fi) * 8 + jh) = *(float2*)o;
}

// ---------------- k_prew: w1 and w2 -> 64-row-group fragment order bf16 (merged launch) ----------------
__global__ __launch_bounds__(64) void k_prew(const float* __restrict__ w1,
                                             const float* __restrict__ w2,
                                             bf16* __restrict__ w1bf,
                                             bf16* __restrict__ w2bf) {
  int bidx = blockIdx.x;
  int lane = threadIdx.x;
  if (bidx < Ff) {
    int f = bidx;                  // 0..2047
    const float* src = w1 + (size_t)f * Dd + lane * 4;
    bf16 o[4] __attribute__((aligned(8)));
#pragma unroll
    for (int u = 0; u < 4; u++) o[u] = f2b(src[u]);
    int s = lane >> 3;
    int q2 = (lane >> 1) & 3;
    int jh = (lane & 1) * 4;
    size_t fi = (size_t)(((f & 63) >> 4) * 64 + q2 * 16 + (f & 15));
    *(float2*)(w1bf + ((size_t)((f >> 6) * 8 + s) * 256 + fi) * 8 + jh) = *(float2*)o;
  } else {
    int d = bidx - Ff;             // 0..255
    const float* src = w2 + (size_t)d * Ff + lane * 32;
    size_t gbase = (size_t)((d >> 6) * 64 + lane) * 256;
    int fbase = ((d & 63) >> 4) * 64 + (d & 15);
#pragma unroll
    for (int q2 = 0; q2 < 4; q2++) {
      float4 v0 = *(const float4*)(src + q2 * 8);
      float4 v1 = *(const float4*)(src + q2 * 8 + 4);
      bf16 o[8] __attribute__((aligned(16)));
      o[0] = f2b(v0.x); o[1] = f2b(v0.y); o[2] = f2b(v0.z); o[3] = f2b(v0.w);
      o[4] = f2b(v1.x); o[5] = f2b(v1.y); o[6] = f2b(v1.z); o[7] = f2b(v1.w);
      *(float4*)(w2bf + (gbase + fbase + q2 * 16) * 8) = *(float4*)o;
    }
  }
}

#define MFMA16(a, b, c) __builtin_amdgcn_mfma_f32_16x16x32_bf16(a, b, c, 0, 0, 0)

// ---------------- k_dots: softmax(slots) -> attn_bf (frag order), xb_bf (frag order), S ----------------
// hw-window 32 variant: acc[4][2] (32 AGPR) -> 4 waves/SIMD via bounds(256,4). grid 4096.
// Staging: thread = (dp, ch); dp = q(row-pair 0..15) + sp(step-parity); each thread stages its
// parity's step of each pair (rows 2q,2q+1 x 4 hw), keeping the proven d-pair u32 packing.
// Pair-wise double buffer (4 step-slots x 1040 bf16), 4 K-loop barriers, same as R5 schedule.
// LDS (16384 B): Bs @0 (8320), ssred @8320 (32*33 f32 = 4224), nxl @12544 (128), red @12672 (1024).
// phase 2: rp @0 (16384 B) attn repack tile (swizzled), single s' phase.
__global__ __launch_bounds__(256, 4) void k_dots(const bf16* __restrict__ tnbf,
                                                 const float* __restrict__ x,
                                                 bf16* __restrict__ xb_bf,
                                                 bf16* __restrict__ attn_bf,
                                                 float* __restrict__ S) {
  __shared__ __align__(16) char smem[16384];
  bf16* Bs = (bf16*)smem;                    // [4][1040]
  float* ssred = (float*)(smem + 8320);      // [32*33]
  float* nxl = (float*)(smem + 12544);       // [32]
  float* red = (float*)(smem + 12672);       // [256]; red2 = red+128
  int b = blockIdx.x >> 7;
  int hw0 = (blockIdx.x & 127) * 32;
  int tid = threadIdx.x;
  int wave = tid >> 6, lane = tid & 63;
  int quad = lane >> 4, nl = lane & 15;

  int dp = tid >> 3;           // 0..31
  int ch = tid & 7;            // 0..7
  int q = dp & 15;             // d row-pair within step
  int sp = dp >> 4;            // step parity (0/1)
  int qb = q >> 2;
  int jb = (q & 3) * 2;

  f32x4 acc[4][2];
#pragma unroll
  for (int i = 0; i < 4; i++)
#pragma unroll
    for (int j = 0; j < 2; j++) acc[i][j] = (f32x4){0.f, 0.f, 0.f, 0.f};
  float ssp[4] = {0.f, 0.f, 0.f, 0.f};

  // xb_bf write coords: s' is single (window = one 32-hw step)
  int spx = hw0 >> 5;
  int q2x = ch >> 1;
  int jx = (ch & 1) * 4;

  const float* xbase = x + (size_t)((b << 8) + 2 * q) * HWw + hw0 + ch * 4;

  // prologue: load own-parity step of pair 0 + tnbf A-frags for s=0
  float4 va, vb;
  {
    const float* xr = xbase + (size_t)(sp * 32) * HWw;
    va = *(const float4*)xr;
    vb = *(const float4*)(xr + HWw);
  }
  short8 afp[4];
  {
    const bf16* ts0 = tnbf + (size_t)(b * 8) * 1024 * 8;
#pragma unroll
    for (int mt = 0; mt < 4; mt++)
      afp[mt] = *(const short8*)(ts0 + (size_t)(((wave << 2) + mt) * 64 + lane) * 8);
  }

#pragma unroll 1
  for (int p = 0; p < 4; p++) {
    bf16* bsb = Bs + (p & 1) * 2 * 1040;
    int s = 2 * p + sp;                    // own step
    bf16 pa[4] __attribute__((aligned(8)));
    bf16 pb[4] __attribute__((aligned(8)));
    // convert + LDS-store own step
    {
      float vva[4] = {va.x, va.y, va.z, va.w};
      float vvb[4] = {vb.x, vb.y, vb.z, vb.w};
#pragma unroll
      for (int jj = 0; jj < 4; jj++) {
        ssp[jj] += vva[jj] * vva[jj] + vvb[jj] * vvb[jj];
        pa[jj] = f2b(vva[jj]);
        pb[jj] = f2b(vvb[jj]);
      }
#pragma unroll
      for (int jj = 0; jj < 4; jj++) {
        int hwl = ch * 4 + jj;             // 0..31
        int nt = hwl >> 4;                 // 0..1
        int li = (qb << 4) | (hwl & 15);
        union { bf16 h[2]; unsigned int u; } pk;
        pk.h[0] = pa[jj];
        pk.h[1] = pb[jj];
        *(unsigned int*)&bsb[sp * 1040 + nt * 520 + li * 8 + jb] = pk.u;
      }
    }
    __syncthreads();   // pair p fully staged (both parities)

    // xb_bf stores for own step (pa/pb die here) — drain at the NEXT barrier
    {
      int d0r = s * 32 + 2 * q;
      int fiA = (d0r >> 4) * 64 + q2x * 16 + (d0r & 15);
      size_t base = ((size_t)(b * 128) + spx) * 1024;
      *(float2*)(xb_bf + (base + fiA) * 8 + jx) = *(float2*)pa;
      *(float2*)(xb_bf + (base + fiA + 1) * 8 + jx) = *(float2*)pb;
    }
    // issue own-parity load for pair p+1 — in flight under the 16 MFMAs below
    if (p < 3) {
      const float* xr = xbase + (size_t)(((p + 1) * 2 + sp) * 32) * HWw;
      va = *(const float4*)xr;
      vb = *(const float4*)(xr + HWw);
    }
    // MFMA for steps 2p, 2p+1 (1-step-ahead tnbf prefetch)
#pragma unroll
    for (int qq = 0; qq < 2; qq++) {
      int ss_ = 2 * p + qq;
      short8 af[4];
#pragma unroll
      for (int mt = 0; mt < 4; mt++) af[mt] = afp[mt];
      if (ss_ < 7) {
        const bf16* tsrc = tnbf + (size_t)(b * 8 + ss_ + 1) * 1024 * 8;
#pragma unroll
        for (int mt = 0; mt < 4; mt++)
          afp[mt] = *(const short8*)(tsrc + (size_t)(((wave << 2) + mt) * 64 + lane) * 8);
      }
      short8 bfv[2];
#pragma unroll
      for (int nt = 0; nt < 2; nt++)
        bfv[nt] = *(const short8*)(bsb + qq * 1040 + nt * 520 + lane * 8);
#pragma unroll
      for (int mt = 0; mt < 4; mt++)
#pragma unroll
        for (int nt = 0; nt < 2; nt++) acc[mt][nt] = MFMA16(af[mt], bfv[nt], acc[mt][nt]);
    }
  }

  // ---- x l2norm denominators (32 pixels; contributors dp = 0..31) ----
#pragma unroll
  for (int jj = 0; jj < 4; jj++) ssred[(ch * 4 + jj) * 33 + dp] = ssp[jj];
  __syncthreads();
  if (tid < 32) {
    float sum = 0.f;
#pragma unroll
    for (int i = 0; i < 32; i++) sum += ssred[tid * 33 + i];
    nxl[tid] = TEMP_INV / fmaxf(sqrtf(sum), NORM_EPSf);
  }
  __syncthreads();

  float sc[2];
#pragma unroll
  for (int nt = 0; nt < 2; nt++) sc[nt] = nxl[nt * 16 + nl];
#pragma unroll
  for (int mt = 0; mt < 4; mt++)
#pragma unroll
    for (int nt = 0; nt < 2; nt++)
#pragma unroll
      for (int r = 0; r < 4; r++) acc[mt][nt][r] *= sc[nt];

  float* red2 = red + 128;

  float pmax[2];
#pragma unroll
  for (int nt = 0; nt < 2; nt++) {
    float m = acc[0][nt][0];
#pragma unroll
    for (int mt = 0; mt < 4; mt++)
#pragma unroll
      for (int r = 0; r < 4; r++) m = fmaxf(m, acc[mt][nt][r]);
    m = fmaxf(m, __shfl_xor(m, 16, 64));
    m = fmaxf(m, __shfl_xor(m, 32, 64));
    pmax[nt] = m;
  }
  if (lane < 16) {
#pragma unroll
    for (int nt = 0; nt < 2; nt++) red[((wave << 1) + nt) * 16 + nl] = pmax[nt];
  }
  __syncthreads();
  float cmax[2];
#pragma unroll
  for (int nt = 0; nt < 2; nt++) {
    float m = red[nt * 16 + nl];
#pragma unroll
    for (int w2 = 1; w2 < 4; w2++) m = fmaxf(m, red[((w2 << 1) + nt) * 16 + nl]);
    cmax[nt] = m;
  }

  float psum[2];
#pragma unroll
  for (int nt = 0; nt < 2; nt++) {
    float s = 0.f;
#pragma unroll
    for (int mt = 0; mt < 4; mt++)
#pragma unroll
      for (int r = 0; r < 4; r++) {
        float e = __expf(acc[mt][nt][r] - cmax[nt]);
        acc[mt][nt][r] = e;
        s += e;
      }
    s += __shfl_xor(s, 16, 64);
    s += __shfl_xor(s, 32, 64);
    psum[nt] = s;
  }
  if (lane < 16) {
#pragma unroll
    for (int nt = 0; nt < 2; nt++) red2[((wave << 1) + nt) * 16 + nl] = psum[nt];
  }
  __syncthreads();
  float ci[2];
#pragma unroll
  for (int nt = 0; nt < 2; nt++) {
    float s = 0.f;
#pragma unroll
    for (int w2 = 0; w2 < 4; w2++) s += red2[((w2 << 1) + nt) * 16 + nl];
    ci[nt] = 1.0f / s;
  }

  // ---- quantize + spatial sums S ----
#pragma unroll
  for (int mt = 0; mt < 4; mt++) {
    int slotg = (b << 8) + (wave << 6) + (mt << 4) + (quad << 2);
#pragma unroll
    for (int r = 0; r < 4; r++) {
      float rs = 0.f;
#pragma unroll
      for (int nt = 0; nt < 2; nt++) {
        bf16 hb = f2b(acc[mt][nt][r] * ci[nt] + EPSf);
        float qv = b2f(hb);
        acc[mt][nt][r] = qv;
        rs += qv;
      }
      rs += __shfl_xor(rs, 1, 64);
      rs += __shfl_xor(rs, 2, 64);
      rs += __shfl_xor(rs, 4, 64);
      rs += __shfl_xor(rs, 8, 64);
      if (nl == 0) atomicAdd(&S[slotg + r], rs);
    }
  }

  // ---- attn epilogue: single s' phase, repack through LDS (swizzled), 16B coalesced flush ----
  __syncthreads();                 // red2 reads done; smem reusable
  bf16* rp = (bf16*)smem;          // [1024 frags][8] bf16 = 16 KB
  int jat = nl & 7;
#pragma unroll
  for (int mt = 0; mt < 4; mt++) {
    int fi0 = ((wave << 2) + mt) * 64 + (quad << 2);
#pragma unroll
    for (int nt = 0; nt < 2; nt++) {
      int q2p = (nt << 1) + (nl >> 3);
#pragma unroll
      for (int r = 0; r < 4; r++) {
        int fi = fi0 + q2p * 16 + r;
        int fisw = fi ^ ((fi >> 3) & 3);
        rp[fisw * 8 + jat] = f2b(acc[mt][nt][r]);
      }
    }
  }
  __syncthreads();
  size_t gbase = ((size_t)(b * 128) + spx) * 1024 * 8;
#pragma unroll
  for (int u = 0; u < 4; u++) {
    int fl = u * 256 + tid;
    int fg = fl ^ ((fl >> 3) & 3);
    short8 vv = *(const short8*)(rp + (size_t)fl * 8);
    *(short8*)(attn_bf + gbase + (size_t)fg * 8) = vv;
  }
}

// ---------------- GEMM2 (MFMA, zero-LDS, hs-4 K-split -> 4 partial buffers, NO atomics) ----------------
__global__ __launch_bounds__(256) void k_gemm2(const bf16* __restrict__ attn_bf,
                                               const bf16* __restrict__ xb_bf,
                                               float* __restrict__ t2p) {
  int n = blockIdx.x;
  int b = n & 31;
  int r2 = n >> 5;                 // 0..63
  int kp = r2 & 3;
  int dgrp = (r2 >> 2) & 3;
  int hs = r2 >> 4;
  int tid = threadIdx.x;
  int wave = tid >> 6, lane = tid & 63;
  int wr = wave >> 1, wc = wave & 1;

  f32x4 acc[2][2];
#pragma unroll
  for (int i = 0; i < 2; i++)
#pragma unroll
    for (int j = 0; j < 2; j++) acc[i][j] = (f32x4){0.f, 0.f, 0.f, 0.f};

  const bf16* Abase = attn_bf + ((size_t)(b * 128 + hs * 32) * 1024 + (size_t)(kp * 4 + wr * 2) * 64) * 8;
  const bf16* Bbase = xb_bf + ((size_t)(b * 128 + hs * 32) * 1024 + (size_t)(dgrp * 4 + wc * 2) * 64) * 8;
#pragma unroll 4
  for (int st = 0; st < 32; st++) {
    const bf16* Ap = Abase + (size_t)st * 1024 * 8;
    const bf16* Bp = Bbase + (size_t)st * 1024 * 8;
    short8 a0 = *(const short8*)(Ap + (size_t)lane * 8);
    short8 a1 = *(const short8*)(Ap + (size_t)(64 + lane) * 8);
    short8 b0 = *(const short8*)(Bp + (size_t)lane * 8);
    short8 b1 = *(const short8*)(Bp + (size_t)(64 + lane) * 8);
    acc[0][0] = MFMA16(a0, b0, acc[0][0]);
    acc[0][1] = MFMA16(a0, b1, acc[0][1]);
    acc[1][0] = MFMA16(a1, b0, acc[1][0]);
    acc[1][1] = MFMA16(a1, b1, acc[1][1]);
  }
  float* dst = t2p + (size_t)hs * PKD;
  int quad = lane >> 4, nl = lane & 15;
#pragma unroll
  for (int i = 0; i < 2; i++)
#pragma unroll
    for (int r = 0; r < 4; r++) {
      int row = (b << 8) + kp * 64 + wr * 32 + i * 16 + quad * 4 + r;
#pragma unroll
      for (int j = 0; j < 2; j++) {
        int col = dgrp * 64 + wc * 32 + j * 16 + nl;
        dst[(size_t)row * Dd + col] = acc[i][j][r];
      }
    }
}

// ---------------- LN_pre: t = LN(sum(t2 partials)/S + tgt); also tbf (64-row-group frag order) ----------------
__global__ __launch_bounds__(64) void k_ln_pre(const float* __restrict__ t2p,
                                               const float* __restrict__ S,
                                               const float* __restrict__ tgt,
                                               const float* __restrict__ g,
                                               const float* __restrict__ be,
                                               float* __restrict__ t,
                                               bf16* __restrict__ tbf) {
  int row = blockIdx.x;
  int lane = threadIdx.x;
  float sInv = 1.0f / S[row];
  size_t off = (size_t)row * Dd + lane * 4;
  float4 a0 = *(const float4*)(t2p + off);
  float4 a1 = *(const float4*)(t2p + PKD + off);
  float4 a2 = *(const float4*)(t2p + 2 * PKD + off);
  float4 a3 = *(const float4*)(t2p + 3 * PKD + off);
  const float* pt = tgt + off;
  float v[4];
  v[0] = (a0.x + a1.x + a2.x + a3.x) * sInv + pt[0];
  v[1] = (a0.y + a1.y + a2.y + a3.y) * sInv + pt[1];
  v[2] = (a0.z + a1.z + a2.z + a3.z) * sInv + pt[2];
  v[3] = (a0.w + a1.w + a2.w + a3.w) * sInv + pt[3];
  float s1 = v[0] + v[1] + v[2] + v[3];
  float s2 = v[0] * v[0] + v[1] * v[1] + v[2] * v[2] + v[3] * v[3];
#pragma unroll
  for (int m = 32; m >= 1; m >>= 1) {
    s1 += __shfl_xor(s1, m, 64);
    s2 += __shfl_xor(s2, m, 64);
  }
  float mu = s1 * (1.0f / 256.0f);
  float var = s2 * (1.0f / 256.0f) - mu * mu;
  float rs = rsqrtf(fmaxf(var, 0.f) + LN_EPSf);
  float* po = t + (size_t)row * Dd + lane * 4;
  bf16 o[4] __attribute__((aligned(8)));
#pragma unroll
  for (int u = 0; u < 4; u++) {
    float val = (v[u] - mu) * rs * g[lane * 4 + u] + be[lane * 4 + u];
    po[u] = val;
    o[u] = f2b(val);
  }
  int s = lane >> 3;
  int q2 = (lane >> 1) & 3;
  int jh = (lane & 1) * 4;
  size_t fi = (size_t)(((row & 63) >> 4) * 64 + q2 * 16 + (row & 15));
  *(float2*)(tbf + ((size_t)((row >> 6) * 8 + s) * 256 + fi) * 8 + jh) = *(float2*)o;
}

// ---------------- k_ffn: FUSED FFN. o2 = relu(t @ w1^T + b1) @ w2^T, h1 never touches HBM ----------------
// grid 256 (rg = 32-row group), 512 threads (8 waves). R10-proven.
__global__ __launch_bounds__(512, 2) void k_ffn(const bf16* __restrict__ tbf,
                                                const bf16* __restrict__ w1bf,
                                                const float* __restrict__ b1,
                                                const bf16* __restrict__ w2bf,
                                                float* __restrict__ o2) {
  __shared__ __align__(16) bf16 rp[2][2 * 128 * 8];   // [buf][set*128 + fi_sw][8]
  int rg = blockIdx.x;             // 0..255 (rows rg*32 .. +31)
  int tid = threadIdx.x;
  int wave = tid >> 6, lane = tid & 63;
  int quad = lane >> 4, nl = lane & 15;
  int mh = wave >> 2, fq = wave & 3;     // GEMM1 role
  int gg = rg >> 1, half = rg & 1;       // tbf 64-row group, half

  short8 af1[8];
  {
    const bf16* Ab = tbf + ((size_t)(gg * 8) * 256 + (size_t)((half * 2 + mh) * 64 + lane)) * 8;
#pragma unroll
    for (int s = 0; s < 8; s++) af1[s] = *(const short8*)(Ab + (size_t)s * 2048);
  }

  f32x4 acc2[2][2];
#pragma unroll
  for (int i = 0; i < 2; i++)
#pragma unroll
    for (int j = 0; j < 2; j++) acc2[i][j] = (f32x4){0.f, 0.f, 0.f, 0.f};

  int setw = fq >> 1;
  int q2w = (fq * 2 + (nl >> 3)) & 3;
  int jw = nl & 7;
  int dgrp2 = wave >> 1;
  int ntp0 = (wave & 1) * 2;

  auto G1 = [&](int cn) {
    f32x4 a1a = (f32x4){0.f, 0.f, 0.f, 0.f};
    f32x4 a1b = (f32x4){0.f, 0.f, 0.f, 0.f};
    const bf16* Bb1 = w1bf + ((size_t)(cn * 8) * 256 + (size_t)(fq * 64 + lane)) * 8;
#pragma unroll
    for (int s = 0; s < 8; s += 2) {
      short8 bv0 = *(const short8*)(Bb1 + (size_t)s * 2048);
      short8 bv1 = *(const short8*)(Bb1 + (size_t)(s + 1) * 2048);
      a1a = MFMA16(af1[s], bv0, a1a);
      a1b = MFMA16(af1[s + 1], bv1, a1b);
    }
    float bias = b1[cn * 64 + fq * 16 + nl];
    bf16* rpw = &rp[cn & 1][0];
#pragma unroll
    for (int r = 0; r < 4; r++) {
      float hv = fmaxf(a1a[r] + a1b[r] + bias, 0.f);
      int fi = mh * 64 + q2w * 16 + quad * 4 + r;
      int fisw = fi ^ ((fi >> 3) & 3);
      rpw[(setw * 128 + fisw) * 8 + jw] = f2b(hv);
    }
  };

  G1(0);
  __syncthreads();

#pragma unroll 1
  for (int c = 0; c < 32; c++) {
    if (c < 31) G1(c + 1);
    const bf16* rpr = &rp[c & 1][0];
#pragma unroll
    for (int ks = 0; ks < 2; ks++) {
      short8 a2[2];
#pragma unroll
      for (int mi = 0; mi < 2; mi++) {
        int fi = mi * 64 + lane;
        int fisw = fi ^ ((fi >> 3) & 3);
        a2[mi] = *(const short8*)(rpr + (ks * 128 + fisw) * 8);
      }
      int sg = c * 2 + ks;
#pragma unroll
      for (int nt = 0; nt < 2; nt++) {
        short8 b2 = *(const short8*)(w2bf + ((size_t)(dgrp2 * 64 + sg) * 256 + (size_t)((ntp0 + nt) * 64 + lane)) * 8);
        acc2[0][nt] = MFMA16(a2[0], b2, acc2[0][nt]);
        acc2[1][nt] = MFMA16(a2[1], b2, acc2[1][nt]);
      }
    }
    __syncthreads();
  }

#pragma unroll
  for (int mi = 0; mi < 2; mi++)
#pragma unroll
    for (int r = 0; r < 4; r++) {
      int row = rg * 32 + mi * 16 + quad * 4 + r;
#pragma unroll
      for (int nt = 0; nt < 2; nt++) {
        int col = wave * 32 + nt * 16 + nl;
        o2[(size_t)row * Dd + col] = acc2[mi][nt][r];
      }
    }
}

// ---------------- LN_out: out = LN(o2 + b2 + t) with g3/be3 ----------------
__global__ __launch_bounds__(64) void k_ln_out(const float* __restrict__ o2,
                                               const float* __restrict__ b2v,
                                               const float* __restrict__ t,
                                               const float* __restrict__ g,
                                               const float* __restrict__ be,
                                               float* __restrict__ out) {
  int row = blockIdx.x;
  int lane = threadIdx.x;
  size_t off = (size_t)row * Dd + lane * 4;
  float4 aq = *(const float4*)(o2 + off);
  const float* pt = t + off;
  float v[4];
  v[0] = aq.x + b2v[lane * 4 + 0] + pt[0];
  v[1] = aq.y + b2v[lane * 4 + 1] + pt[1];
  v[2] = aq.z + b2v[lane * 4 + 2] + pt[2];
  v[3] = aq.w + b2v[lane * 4 + 3] + pt[3];
  float s1 = v[0] + v[1] + v[2] + v[3];
  float s2 = v[0] * v[0] + v[1] * v[1] + v[2] * v[2] + v[3] * v[3];
#pragma unroll
  for (int m = 32; m >= 1; m >>= 1) {
    s1 += __shfl_xor(s1, m, 64);
    s2 += __shfl_xor(s2, m, 64);
  }
  float mu = s1 * (1.0f / 256.0f);
  float var = s2 * (1.0f / 256.0f) - mu * mu;
  float rs = rsqrtf(fmaxf(var, 0.f) + LN_EPSf);
  float* pw = out + (size_t)row * Dd + lane * 4;
#pragma unroll
  for (int u = 0; u < 4; u++)
    pw[u] = (v[u] - mu) * rs * g[lane * 4 + u] + be[lane * 4 + u];
}

extern "C" void kernel_launch(void* const* d_in, const int* in_sizes, int n_in,
                              void* d_out, int out_size, void* d_ws, size_t ws_size,
                              hipStream_t stream) {
  const float* x = (const float*)d_in[0];
  const float* tgt = (const float*)d_in[1];
  const float* w1 = (const float*)d_in[2];
  const float* b1 = (const float*)d_in[3];
  const float* w2 = (const float*)d_in[4];
  const float* b2v = (const float*)d_in[5];
  const float* g2 = (const float*)d_in[6];
  const float* be2 = (const float*)d_in[7];
  const float* g3 = (const float*)d_in[8];
  const float* be3 = (const float*)d_in[9];
  float* out = (float*)d_out;

  // Aliasing:
  //   tbf -> tnbf (dead after k_dots)
  //   w1bf/w2bf carved from attn_bf head (attn dead after gemm2; prew runs after gemm2)
  //   t2 partials (4x8MB = 32MB) -> h1reg region (read by ln_pre; region otherwise unused now)
  //   o2 (8MB) -> xb_bf region (xb dead after gemm2)
  char* w = (char*)d_ws;
  bf16* tnbf = (bf16*)w;     w += (size_t)Bb * Kk * Dd * 2;   // 4 MB
  float* S = (float*)w;      w += (size_t)Bb * Kk * 4;        // 32 KB
  float* t = (float*)w;      w += (size_t)Bb * Kk * Dd * 4;   // 8 MB
  bf16* attn_bf = (bf16*)w;  w += (size_t)Bb * HWw * Kk * 2;  // 64 MB
  bf16* h1reg = (bf16*)w;    w += (size_t)Bb * Kk * Ff * 2;   // 32 MB (t2p lives here)
  bf16* xb_bf = (bf16*)w;    w += (size_t)Bb * Dd * HWw * 2;  // 64 MB

  bf16* tbf = tnbf;                        // 4 MB alias
  bf16* w1bf = attn_bf;                    // 1 MB carve
  bf16* w2bf = attn_bf + (size_t)Ff * Dd;  // 1 MB carve
  float* t2p = (float*)h1reg;              // 32 MB alias (4 partials)
  float* o2 = (float*)xb_bf;               // 8 MB alias

  hipMemsetAsync(S, 0, (size_t)Bb * Kk * 4, stream);
  k_tn<<<Bb * Kk, 64, 0, stream>>>(tgt, tnbf);
  k_dots<<<Bb * (HWw / 32), 256, 0, stream>>>(tnbf, x, xb_bf, attn_bf, S);
  k_gemm2<<<2048, 256, 0, stream>>>(attn_bf, xb_bf, t2p);
  k_prew<<<Ff + Dd, 64, 0, stream>>>(w1, w2, w1bf, w2bf);
  k_ln_pre<<<Bb * Kk, 64, 0, stream>>>(t2p, S, tgt, g2, be2, t, tbf);
  k_ffn<<<(Bb * Kk) / 32, 512, 0, stream>>>(tbf, w1bf, b1, w2bf, o2);
  k_ln_out<<<Bb * Kk, 64, 0, stream>>>(o2, b2v, t, g3, be3, out);
}

// Round 12
// 392.815 us; speedup vs baseline: 1.0475x; 1.0475x over previous
//
#include <hip/hip_runtime.h>
#include <hip/hip_bf16.h>

using bf16 = __hip_bfloat16;

typedef __attribute__((ext_vector_type(8))) short short8;
typedef __attribute__((ext_vector_type(4))) float f32x4;

constexpr int Bb = 32, Dd = 256, HWw = 4096, Kk = 256, Ff = 2048;
constexpr float TEMP_INV = 1.0f / 0.07f;
constexpr float EPSf = 1e-6f;
constexpr float NORM_EPSf = 1e-12f;
constexpr float LN_EPSf = 1e-5f;
constexpr size_t PKD = (size_t)Bb * Kk * Dd;   // one t2 partial (2M floats = 8 MB)

static __device__ __forceinline__ float b2f(bf16 v) { return __bfloat162float(v); }
static __device__ __forceinline__ bf16 f2b(float v) { return __float2bfloat16(v); }

// Fragment-order conventions (16x16x32 MFMA, K-step 32):
//   element (row, k): set = k>>5, q2 = (k>>3)&3, j = k&7
//   256-row group (tnbf, attn_bf, xb_bf): fi = (row>>4)*64 + q2*16 + (row&15); 1024 frags/step
//   64-row group (tbf/w1bf/w2bf):         fi = ((row&63)>>4)*64 + q2*16 + (row&15); 256 frags/step
//   32-row group (k_ffn rp tile):         fi = ((row&31)>>4)*64 + q2*16 + (row&15); 128 frags/set
// Reader identity: addr = set_base + (mtile_local*64 + lane)*8  (lane = q2*16 + row&15)
// LDS repack swizzle (bank-spread, involution): fi_sw = fi ^ ((fi>>3)&3)
//
// Config provenance (measured, final):
//   k_dots: R5/R10 pair-wise hw-64 + bounds(256,3), VGPR 80 -> 91-106 us session-dependent.
//     R11 hw-32 (occupancy 37%) REGRESSED to 112 us: occupancy was not the binding constraint
//     (per-block compute:load ratio halved; write amplification +8MB). R6 superstep SPILLED.
//   k_gemm2: R8 hs-4 K-split partials, grid 2048.
//   k_ffn: fused ffn1+ffn2 (h1 64MB HBM round-trip removed; repack stays in LDS).
//   Best harness-verified total: 391.57 us (R10, this exact source).

// ---------------- k_tn: tnbf = l2norm(tgt) bf16, 256-row-group fragment order ----------------
__global__ __launch_bounds__(64) void k_tn(const float* __restrict__ tgt,
                                           bf16* __restrict__ tnbf) {
  int row = blockIdx.x;            // b*256 + slot
  int b = row >> 8, slot = row & 255;
  int lane = threadIdx.x;
  const float* src = tgt + (size_t)row * Dd + lane * 4;
  float v[4];
#pragma unroll
  for (int u = 0; u < 4; u++) v[u] = src[u];
  float ss = v[0] * v[0] + v[1] * v[1] + v[2] * v[2] + v[3] * v[3];
#pragma unroll
  for (int m = 32; m >= 1; m >>= 1) ss += __shfl_xor(ss, m, 64);
  float inv = 1.0f / fmaxf(sqrtf(ss), NORM_EPSf);
  bf16 o[4] __attribute__((aligned(8)));
#pragma unroll
  for (int u = 0; u < 4; u++) o[u] = f2b(v[u] * inv);
  int s = lane >> 3;
  int q2 = (lane >> 1) & 3;
  int jh = (lane & 1) * 4;
  size_t fi = (size_t)((slot >> 4) * 64 + q2 * 16 + (slot & 15));
  *(float2*)(tnbf + ((size_t)(b * 8 + s) * 1024 + fi) * 8 + jh) = *(float2*)o;
}

// ---------------- k_prew: w1 and w2 -> 64-row-group fragment order bf16 (merged launch) ----------------
__global__ __launch_bounds__(64) void k_prew(const float* __restrict__ w1,
                                             const float* __restrict__ w2,
                                             bf16* __restrict__ w1bf,
                                             bf16* __restrict__ w2bf) {
  int bidx = blockIdx.x;
  int lane = threadIdx.x;
  if (bidx < Ff) {
    int f = bidx;                  // 0..2047
    const float* src = w1 + (size_t)f * Dd + lane * 4;
    bf16 o[4] __attribute__((aligned(8)));
#pragma unroll
    for (int u = 0; u < 4; u++) o[u] = f2b(src[u]);
    int s = lane >> 3;
    int q2 = (lane >> 1) & 3;
    int jh = (lane & 1) * 4;
    size_t fi = (size_t)(((f & 63) >> 4) * 64 + q2 * 16 + (f & 15));
    *(float2*)(w1bf + ((size_t)((f >> 6) * 8 + s) * 256 + fi) * 8 + jh) = *(float2*)o;
  } else {
    int d = bidx - Ff;             // 0..255
    const float* src = w2 + (size_t)d * Ff + lane * 32;
    size_t gbase = (size_t)((d >> 6) * 64 + lane) * 256;
    int fbase = ((d & 63) >> 4) * 64 + (d & 15);
#pragma unroll
    for (int q2 = 0; q2 < 4; q2++) {
      float4 v0 = *(const float4*)(src + q2 * 8);
      float4 v1 = *(const float4*)(src + q2 * 8 + 4);
      bf16 o[8] __attribute__((aligned(16)));
      o[0] = f2b(v0.x); o[1] = f2b(v0.y); o[2] = f2b(v0.z); o[3] = f2b(v0.w);
      o[4] = f2b(v1.x); o[5] = f2b(v1.y); o[6] = f2b(v1.z); o[7] = f2b(v1.w);
      *(float4*)(w2bf + (gbase + fbase + q2 * 16) * 8) = *(float4*)o;
    }
  }
}

#define MFMA16(a, b, c) __builtin_amdgcn_mfma_f32_16x16x32_bf16(a, b, c, 0, 0, 0)

// ---------------- k_dots: softmax(slots) -> attn_bf (frag order), xb_bf (frag order), S ----------------
// R5 config: pair-wise double-buffered pipeline at 3 waves/SIMD, bounds(256,3), VGPR 80.
__global__ __launch_bounds__(256, 3) void k_dots(const bf16* __restrict__ tnbf,
                                                 const float* __restrict__ x,
                                                 bf16* __restrict__ xb_bf,
                                                 bf16* __restrict__ attn_bf,
                                                 float* __restrict__ S) {
  __shared__ __align__(16) char smem[23296];
  bf16* Bs = (bf16*)smem;                    // [4][2080]
  float* ssred = (float*)(smem + 16640);     // [64*17]
  float* nxl = (float*)(smem + 20992);       // [64]
  float* red = (float*)(smem + 21248);       // [512]
  int b = blockIdx.x >> 6;
  int hw0 = (blockIdx.x & 63) * 64;
  int tid = threadIdx.x;
  int wave = tid >> 6, lane = tid & 63;
  int quad = lane >> 4, nl = lane & 15;

  int dp = tid >> 4;           // 0..15
  int ch = tid & 15;           // 0..15
  int qb = dp >> 2;
  int jb = (dp & 3) * 2;

  f32x4 acc[4][4];
#pragma unroll
  for (int i = 0; i < 4; i++)
#pragma unroll
    for (int j = 0; j < 4; j++) acc[i][j] = (f32x4){0.f, 0.f, 0.f, 0.f};
  float ssp[4] = {0.f, 0.f, 0.f, 0.f};

  int spx = (hw0 >> 5) + (ch >> 3);
  int q2x = (ch >> 1) & 3;
  int jx = (ch & 1) * 4;

  const float* xbase = x + (size_t)((b << 8) + 2 * dp) * HWw + hw0 + ch * 4;
  float4 va4[2], vb4[2];
#pragma unroll
  for (int q = 0; q < 2; q++) {
    const float* xr = xbase + (size_t)(q * 32) * HWw;
    va4[q] = *(const float4*)xr;
    vb4[q] = *(const float4*)(xr + HWw);
  }
  short8 afp[4];
  {
    const bf16* ts0 = tnbf + (size_t)(b * 8) * 1024 * 8;
#pragma unroll
    for (int mt = 0; mt < 4; mt++)
      afp[mt] = *(const short8*)(ts0 + (size_t)(((wave << 2) + mt) * 64 + lane) * 8);
  }

#pragma unroll 1
  for (int p = 0; p < 4; p++) {
    bf16* bsb = Bs + (p & 1) * 2 * 2080;
    bf16 paS[2][4] __attribute__((aligned(8)));
    bf16 pbS[2][4] __attribute__((aligned(8)));
#pragma unroll
    for (int q = 0; q < 2; q++) {
      float vva[4] = {va4[q].x, va4[q].y, va4[q].z, va4[q].w};
      float vvb[4] = {vb4[q].x, vb4[q].y, vb4[q].z, vb4[q].w};
#pragma unroll
      for (int jj = 0; jj < 4; jj++) {
        ssp[jj] += vva[jj] * vva[jj] + vvb[jj] * vvb[jj];
        paS[q][jj] = f2b(vva[jj]);
        pbS[q][jj] = f2b(vvb[jj]);
      }
#pragma unroll
      for (int jj = 0; jj < 4; jj++) {
        int hwl = ch * 4 + jj;
        int nt = hwl >> 4;
        int li = (qb << 4) | (hwl & 15);
        union { bf16 h[2]; unsigned int u; } pk;
        pk.h[0] = paS[q][jj];
        pk.h[1] = pbS[q][jj];
        *(unsigned int*)&bsb[q * 2080 + nt * 520 + li * 8 + jb] = pk.u;
      }
    }
    __syncthreads();

#pragma unroll
    for (int q = 0; q < 2; q++) {
      int s = 2 * p + q;
      int d0r = s * 32 + 2 * dp;
      int fiA = (d0r >> 4) * 64 + q2x * 16 + (d0r & 15);
      size_t base = ((size_t)(b * 128) + spx) * 1024;
      *(float2*)(xb_bf + (base + fiA) * 8 + jx) = *(float2*)paS[q];
      *(float2*)(xb_bf + (base + fiA + 1) * 8 + jx) = *(float2*)pbS[q];
    }
    if (p < 3) {
#pragma unroll
      for (int q = 0; q < 2; q++) {
        const float* xr = xbase + (size_t)(((p + 1) * 2 + q) * 32) * HWw;
        va4[q] = *(const float4*)xr;
        vb4[q] = *(const float4*)(xr + HWw);
      }
    }
#pragma unroll
    for (int q = 0; q < 2; q++) {
      int s = 2 * p + q;
      short8 af[4];
#pragma unroll
      for (int mt = 0; mt < 4; mt++) af[mt] = afp[mt];
      if (s < 7) {
        const bf16* tsrc = tnbf + (size_t)(b * 8 + s + 1) * 1024 * 8;
#pragma unroll
        for (int mt = 0; mt < 4; mt++)
          afp[mt] = *(const short8*)(tsrc + (size_t)(((wave << 2) + mt) * 64 + lane) * 8);
      }
      short8 bfv[4];
#pragma unroll
      for (int nt = 0; nt < 4; nt++)
        bfv[nt] = *(const short8*)(bsb + q * 2080 + nt * 520 + lane * 8);
#pragma unroll
      for (int mt = 0; mt < 4; mt++)
#pragma unroll
        for (int nt = 0; nt < 4; nt++) acc[mt][nt] = MFMA16(af[mt], bfv[nt], acc[mt][nt]);
    }
  }

#pragma unroll
  for (int jj = 0; jj < 4; jj++) ssred[(ch * 4 + jj) * 17 + dp] = ssp[jj];
  __syncthreads();
  if (tid < 64) {
    float sum = 0.f;
#pragma unroll
    for (int i = 0; i < 16; i++) sum += ssred[tid * 17 + i];
    nxl[tid] = TEMP_INV / fmaxf(sqrtf(sum), NORM_EPSf);
  }
  __syncthreads();

  float sc[4];
#pragma unroll
  for (int nt = 0; nt < 4; nt++) sc[nt] = nxl[nt * 16 + nl];
#pragma unroll
  for (int mt = 0; mt < 4; mt++)
#pragma unroll
    for (int nt = 0; nt < 4; nt++)
#pragma unroll
      for (int r = 0; r < 4; r++) acc[mt][nt][r] *= sc[nt];

  float* red2 = red + 256;

  float pmax[4];
#pragma unroll
  for (int nt = 0; nt < 4; nt++) {
    float m = acc[0][nt][0];
#pragma unroll
    for (int mt = 0; mt < 4; mt++)
#pragma unroll
      for (int r = 0; r < 4; r++) m = fmaxf(m, acc[mt][nt][r]);
    m = fmaxf(m, __shfl_xor(m, 16, 64));
    m = fmaxf(m, __shfl_xor(m, 32, 64));
    pmax[nt] = m;
  }
  if (lane < 16) {
#pragma unroll
    for (int nt = 0; nt < 4; nt++) red[((wave << 2) + nt) * 16 + nl] = pmax[nt];
  }
  __syncthreads();
  float cmax[4];
#pragma unroll
  for (int nt = 0; nt < 4; nt++) {
    float m = red[nt * 16 + nl];
#pragma unroll
    for (int w2 = 1; w2 < 4; w2++) m = fmaxf(m, red[((w2 << 2) + nt) * 16 + nl]);
    cmax[nt] = m;
  }

  float psum[4];
#pragma unroll
  for (int nt = 0; nt < 4; nt++) {
    float s = 0.f;
#pragma unroll
    for (int mt = 0; mt < 4; mt++)
#pragma unroll
      for (int r = 0; r < 4; r++) {
        float e = __expf(acc[mt][nt][r] - cmax[nt]);
        acc[mt][nt][r] = e;
        s += e;
      }
    s += __shfl_xor(s, 16, 64);
    s += __shfl_xor(s, 32, 64);
    psum[nt] = s;
  }
  if (lane < 16) {
#pragma unroll
    for (int nt = 0; nt < 4; nt++) red2[((wave << 2) + nt) * 16 + nl] = psum[nt];
  }
  __syncthreads();
  float ci[4];
#pragma unroll
  for (int nt = 0; nt < 4; nt++) {
    float s = 0.f;
#pragma unroll
    for (int w2 = 0; w2 < 4; w2++) s += red2[((w2 << 2) + nt) * 16 + nl];
    ci[nt] = 1.0f / s;
  }

#pragma unroll
  for (int mt = 0; mt < 4; mt++) {
    int slotg = (b << 8) + (wave << 6) + (mt << 4) + (quad << 2);
#pragma unroll
    for (int r = 0; r < 4; r++) {
      float rs = 0.f;
#pragma unroll
      for (int nt = 0; nt < 4; nt++) {
        bf16 hb = f2b(acc[mt][nt][r] * ci[nt] + EPSf);
        float q = b2f(hb);
        acc[mt][nt][r] = q;
        rs += q;
      }
      rs += __shfl_xor(rs, 1, 64);
      rs += __shfl_xor(rs, 2, 64);
      rs += __shfl_xor(rs, 4, 64);
      rs += __shfl_xor(rs, 8, 64);
      if (nl == 0) atomicAdd(&S[slotg + r], rs);
    }
  }

  __syncthreads();
  bf16* rp = (bf16*)smem;
  int jat = nl & 7;
#pragma unroll
  for (int h = 0; h < 2; h++) {
#pragma unroll
    for (int mt = 0; mt < 4; mt++) {
      int fi0 = ((wave << 2) + mt) * 64 + (quad << 2);
#pragma unroll
      for (int ntl = 0; ntl < 2; ntl++) {
        int nt = (h << 1) + ntl;
        int q2p = (ntl << 1) + (nl >> 3);
#pragma unroll
        for (int r = 0; r < 4; r++) {
          int fi = fi0 + q2p * 16 + r;
          int fisw = fi ^ ((fi >> 3) & 3);
          rp[fisw * 8 + jat] = f2b(acc[mt][nt][r]);
        }
      }
    }
    __syncthreads();
    size_t gbase = ((size_t)(b * 128) + (hw0 >> 5) + h) * 1024 * 8;
#pragma unroll
    for (int u = 0; u < 4; u++) {
      int fl = u * 256 + tid;
      int fg = fl ^ ((fl >> 3) & 3);
      short8 vv = *(const short8*)(rp + (size_t)fl * 8);
      *(short8*)(attn_bf + gbase + (size_t)fg * 8) = vv;
    }
    if (h == 0) __syncthreads();
  }
}

// ---------------- GEMM2 (MFMA, zero-LDS, hs-4 K-split -> 4 partial buffers, NO atomics) ----------------
__global__ __launch_bounds__(256) void k_gemm2(const bf16* __restrict__ attn_bf,
                                               const bf16* __restrict__ xb_bf,
                                               float* __restrict__ t2p) {
  int n = blockIdx.x;
  int b = n & 31;
  int r2 = n >> 5;                 // 0..63
  int kp = r2 & 3;
  int dgrp = (r2 >> 2) & 3;
  int hs = r2 >> 4;
  int tid = threadIdx.x;
  int wave = tid >> 6, lane = tid & 63;
  int wr = wave >> 1, wc = wave & 1;

  f32x4 acc[2][2];
#pragma unroll
  for (int i = 0; i < 2; i++)
#pragma unroll
    for (int j = 0; j < 2; j++) acc[i][j] = (f32x4){0.f, 0.f, 0.f, 0.f};

  const bf16* Abase = attn_bf + ((size_t)(b * 128 + hs * 32) * 1024 + (size_t)(kp * 4 + wr * 2) * 64) * 8;
  const bf16* Bbase = xb_bf + ((size_t)(b * 128 + hs * 32) * 1024 + (size_t)(dgrp * 4 + wc * 2) * 64) * 8;
#pragma unroll 4
  for (int st = 0; st < 32; st++) {
    const bf16* Ap = Abase + (size_t)st * 1024 * 8;
    const bf16* Bp = Bbase + (size_t)st * 1024 * 8;
    short8 a0 = *(const short8*)(Ap + (size_t)lane * 8);
    short8 a1 = *(const short8*)(Ap + (size_t)(64 + lane) * 8);
    short8 b0 = *(const short8*)(Bp + (size_t)lane * 8);
    short8 b1 = *(const short8*)(Bp + (size_t)(64 + lane) * 8);
    acc[0][0] = MFMA16(a0, b0, acc[0][0]);
    acc[0][1] = MFMA16(a0, b1, acc[0][1]);
    acc[1][0] = MFMA16(a1, b0, acc[1][0]);
    acc[1][1] = MFMA16(a1, b1, acc[1][1]);
  }
  float* dst = t2p + (size_t)hs * PKD;
  int quad = lane >> 4, nl = lane & 15;
#pragma unroll
  for (int i = 0; i < 2; i++)
#pragma unroll
    for (int r = 0; r < 4; r++) {
      int row = (b << 8) + kp * 64 + wr * 32 + i * 16 + quad * 4 + r;
#pragma unroll
      for (int j = 0; j < 2; j++) {
        int col = dgrp * 64 + wc * 32 + j * 16 + nl;
        dst[(size_t)row * Dd + col] = acc[i][j][r];
      }
    }
}

// ---------------- LN_pre: t = LN(sum(t2 partials)/S + tgt); also tbf (64-row-group frag order) ----------------
__global__ __launch_bounds__(64) void k_ln_pre(const float* __restrict__ t2p,
                                               const float* __restrict__ S,
                                               const float* __restrict__ tgt,
                                               const float* __restrict__ g,
                                               const float* __restrict__ be,
                                               float* __restrict__ t,
                                               bf16* __restrict__ tbf) {
  int row = blockIdx.x;
  int lane = threadIdx.x;
  float sInv = 1.0f / S[row];
  size_t off = (size_t)row * Dd + lane * 4;
  float4 a0 = *(const float4*)(t2p + off);
  float4 a1 = *(const float4*)(t2p + PKD + off);
  float4 a2 = *(const float4*)(t2p + 2 * PKD + off);
  float4 a3 = *(const float4*)(t2p + 3 * PKD + off);
  const float* pt = tgt + off;
  float v[4];
  v[0] = (a0.x + a1.x + a2.x + a3.x) * sInv + pt[0];
  v[1] = (a0.y + a1.y + a2.y + a3.y) * sInv + pt[1];
  v[2] = (a0.z + a1.z + a2.z + a3.z) * sInv + pt[2];
  v[3] = (a0.w + a1.w + a2.w + a3.w) * sInv + pt[3];
  float s1 = v[0] + v[1] + v[2] + v[3];
  float s2 = v[0] * v[0] + v[1] * v[1] + v[2] * v[2] + v[3] * v[3];
#pragma unroll
  for (int m = 32; m >= 1; m >>= 1) {
    s1 += __shfl_xor(s1, m, 64);
    s2 += __shfl_xor(s2, m, 64);
  }
  float mu = s1 * (1.0f / 256.0f);
  float var = s2 * (1.0f / 256.0f) - mu * mu;
  float rs = rsqrtf(fmaxf(var, 0.f) + LN_EPSf);
  float* po = t + (size_t)row * Dd + lane * 4;
  bf16 o[4] __attribute__((aligned(8)));
#pragma unroll
  for (int u = 0; u < 4; u++) {
    float val = (v[u] - mu) * rs * g[lane * 4 + u] + be[lane * 4 + u];
    po[u] = val;
    o[u] = f2b(val);
  }
  int s = lane >> 3;
  int q2 = (lane >> 1) & 3;
  int jh = (lane & 1) * 4;
  size_t fi = (size_t)(((row & 63) >> 4) * 64 + q2 * 16 + (row & 15));
  *(float2*)(tbf + ((size_t)((row >> 6) * 8 + s) * 256 + fi) * 8 + jh) = *(float2*)o;
}

// ---------------- k_ffn: FUSED FFN. o2 = relu(t @ w1^T + b1) @ w2^T, h1 never touches HBM ----------------
// grid 256 (rg = 32-row group), 512 threads (8 waves). R10-proven.
__global__ __launch_bounds__(512, 2) void k_ffn(const bf16* __restrict__ tbf,
                                                const bf16* __restrict__ w1bf,
                                                const float* __restrict__ b1,
                                                const bf16* __restrict__ w2bf,
                                                float* __restrict__ o2) {
  __shared__ __align__(16) bf16 rp[2][2 * 128 * 8];   // [buf][set*128 + fi_sw][8]
  int rg = blockIdx.x;             // 0..255 (rows rg*32 .. +31)
  int tid = threadIdx.x;
  int wave = tid >> 6, lane = tid & 63;
  int quad = lane >> 4, nl = lane & 15;
  int mh = wave >> 2, fq = wave & 3;     // GEMM1 role
  int gg = rg >> 1, half = rg & 1;       // tbf 64-row group, half

  short8 af1[8];
  {
    const bf16* Ab = tbf + ((size_t)(gg * 8) * 256 + (size_t)((half * 2 + mh) * 64 + lane)) * 8;
#pragma unroll
    for (int s = 0; s < 8; s++) af1[s] = *(const short8*)(Ab + (size_t)s * 2048);
  }

  f32x4 acc2[2][2];
#pragma unroll
  for (int i = 0; i < 2; i++)
#pragma unroll
    for (int j = 0; j < 2; j++) acc2[i][j] = (f32x4){0.f, 0.f, 0.f, 0.f};

  int setw = fq >> 1;
  int q2w = (fq * 2 + (nl >> 3)) & 3;
  int jw = nl & 7;
  int dgrp2 = wave >> 1;
  int ntp0 = (wave & 1) * 2;

  auto G1 = [&](int cn) {
    f32x4 a1a = (f32x4){0.f, 0.f, 0.f, 0.f};
    f32x4 a1b = (f32x4){0.f, 0.f, 0.f, 0.f};
    const bf16* Bb1 = w1bf + ((size_t)(cn * 8) * 256 + (size_t)(fq * 64 + lane)) * 8;
#pragma unroll
    for (int s = 0; s < 8; s += 2) {
      short8 bv0 = *(const short8*)(Bb1 + (size_t)s * 2048);
      short8 bv1 = *(const short8*)(Bb1 + (size_t)(s + 1) * 2048);
      a1a = MFMA16(af1[s], bv0, a1a);
      a1b = MFMA16(af1[s + 1], bv1, a1b);
    }
    float bias = b1[cn * 64 + fq * 16 + nl];
    bf16* rpw = &rp[cn & 1][0];
#pragma unroll
    for (int r = 0; r < 4; r++) {
      float hv = fmaxf(a1a[r] + a1b[r] + bias, 0.f);
      int fi = mh * 64 + q2w * 16 + quad * 4 + r;
      int fisw = fi ^ ((fi >> 3) & 3);
      rpw[(setw * 128 + fisw) * 8 + jw] = f2b(hv);
    }
  };

  G1(0);
  __syncthreads();

#pragma unroll 1
  for (int c = 0; c < 32; c++) {
    if (c < 31) G1(c + 1);
    const bf16* rpr = &rp[c & 1][0];
#pragma unroll
    for (int ks = 0; ks < 2; ks++) {
      short8 a2[2];
#pragma unroll
      for (int mi = 0; mi < 2; mi++) {
        int fi = mi * 64 + lane;
        int fisw = fi ^ ((fi >> 3) & 3);
        a2[mi] = *(const short8*)(rpr + (ks * 128 + fisw) * 8);
      }
      int sg = c * 2 + ks;
#pragma unroll
      for (int nt = 0; nt < 2; nt++) {
        short8 b2 = *(const short8*)(w2bf + ((size_t)(dgrp2 * 64 + sg) * 256 + (size_t)((ntp0 + nt) * 64 + lane)) * 8);
        acc2[0][nt] = MFMA16(a2[0], b2, acc2[0][nt]);
        acc2[1][nt] = MFMA16(a2[1], b2, acc2[1][nt]);
      }
    }
    __syncthreads();
  }

#pragma unroll
  for (int mi = 0; mi < 2; mi++)
#pragma unroll
    for (int r = 0; r < 4; r++) {
      int row = rg * 32 + mi * 16 + quad * 4 + r;
#pragma unroll
      for (int nt = 0; nt < 2; nt++) {
        int col = wave * 32 + nt * 16 + nl;
        o2[(size_t)row * Dd + col] = acc2[mi][nt][r];
      }
    }
}

// ---------------- LN_out: out = LN(o2 + b2 + t) with g3/be3 ----------------
__global__ __launch_bounds__(64) void k_ln_out(const float* __restrict__ o2,
                                               const float* __restrict__ b2v,
                                               const float* __restrict__ t,
                                               const float* __restrict__ g,
                                               const float* __restrict__ be,
                                               float* __restrict__ out) {
  int row = blockIdx.x;
  int lane = threadIdx.x;
  size_t off = (size_t)row * Dd + lane * 4;
  float4 aq = *(const float4*)(o2 + off);
  const float* pt = t + off;
  float v[4];
  v[0] = aq.x + b2v[lane * 4 + 0] + pt[0];
  v[1] = aq.y + b2v[lane * 4 + 1] + pt[1];
  v[2] = aq.z + b2v[lane * 4 + 2] + pt[2];
  v[3] = aq.w + b2v[lane * 4 + 3] + pt[3];
  float s1 = v[0] + v[1] + v[2] + v[3];
  float s2 = v[0] * v[0] + v[1] * v[1] + v[2] * v[2] + v[3] * v[3];
#pragma unroll
  for (int m = 32; m >= 1; m >>= 1) {
    s1 += __shfl_xor(s1, m, 64);
    s2 += __shfl_xor(s2, m, 64);
  }
  float mu = s1 * (1.0f / 256.0f);
  float var = s2 * (1.0f / 256.0f) - mu * mu;
  float rs = rsqrtf(fmaxf(var, 0.f) + LN_EPSf);
  float* pw = out + (size_t)row * Dd + lane * 4;
#pragma unroll
  for (int u = 0; u < 4; u++)
    pw[u] = (v[u] - mu) * rs * g[lane * 4 + u] + be[lane * 4 + u];
}

extern "C" void kernel_launch(void* const* d_in, const int* in_sizes, int n_in,
                              void* d_out, int out_size, void* d_ws, size_t ws_size,
                              hipStream_t stream) {
  const float* x = (const float*)d_in[0];
  const float* tgt = (const float*)d_in[1];
  const float* w1 = (const float*)d_in[2];
  const float* b1 = (const float*)d_in[3];
  const float* w2 = (const float*)d_in[4];
  const float* b2v = (const float*)d_in[5];
  const float* g2 = (const float*)d_in[6];
  const float* be2 = (const float*)d_in[7];
  const float* g3 = (const float*)d_in[8];
  const float* be3 = (const float*)d_in[9];
  float* out = (float*)d_out;

  // Aliasing:
  //   tbf -> tnbf (dead after k_dots)
  //   w1bf/w2bf carved from attn_bf head (attn dead after gemm2; prew runs after gemm2)
  //   t2 partials (4x8MB = 32MB) -> h1reg region (read by ln_pre; region otherwise unused now)
  //   o2 (8MB) -> xb_bf region (xb dead after gemm2)
  char* w = (char*)d_ws;
  bf16* tnbf = (bf16*)w;     w += (size_t)Bb * Kk * Dd * 2;   // 4 MB
  float* S = (float*)w;      w += (size_t)Bb * Kk * 4;        // 32 KB
  float* t = (float*)w;      w += (size_t)Bb * Kk * Dd * 4;   // 8 MB
  bf16* attn_bf = (bf16*)w;  w += (size_t)Bb * HWw * Kk * 2;  // 64 MB
  bf16* h1reg = (bf16*)w;    w += (size_t)Bb * Kk * Ff * 2;   // 32 MB (t2p lives here)
  bf16* xb_bf = (bf16*)w;    w += (size_t)Bb * Dd * HWw * 2;  // 64 MB

  bf16* tbf = tnbf;                        // 4 MB alias
  bf16* w1bf = attn_bf;                    // 1 MB carve
  bf16* w2bf = attn_bf + (size_t)Ff * Dd;  // 1 MB carve
  float* t2p = (float*)h1reg;              // 32 MB alias (4 partials)
  float* o2 = (float*)xb_bf;               // 8 MB alias

  hipMemsetAsync(S, 0, (size_t)Bb * Kk * 4, stream);
  k_tn<<<Bb * Kk, 64, 0, stream>>>(tgt, tnbf);
  k_dots<<<Bb * (HWw / 64), 256, 0, stream>>>(tnbf, x, xb_bf, attn_bf, S);
  k_gemm2<<<2048, 256, 0, stream>>>(attn_bf, xb_bf, t2p);
  k_prew<<<Ff + Dd, 64, 0, stream>>>(w1, w2, w1bf, w2bf);
  k_ln_pre<<<Bb * Kk, 64, 0, stream>>>(t2p, S, tgt, g2, be2, t, tbf);
  k_ffn<<<(Bb * Kk) / 32, 512, 0, stream>>>(tbf, w1bf, b1, w2bf, o2);
  k_ln_out<<<Bb * Kk, 64, 0, stream>>>(o2, b2v, t, g3, be3, out);
}

// Round 13
// 388.860 us; speedup vs baseline: 1.0582x; 1.0102x over previous
//
#include <hip/hip_runtime.h>
#include <hip/hip_bf16.h>

using bf16 = __hip_bfloat16;

typedef __attribute__((ext_vector_type(8))) short short8;
typedef __attribute__((ext_vector_type(4))) float f32x4;

constexpr int Bb = 32, Dd = 256, HWw = 4096, Kk = 256, Ff = 2048;
constexpr float TEMP_INV = 1.0f / 0.07f;
constexpr float EPSf = 1e-6f;
constexpr float NORM_EPSf = 1e-12f;
constexpr float LN_EPSf = 1e-5f;
constexpr size_t PKD = (size_t)Bb * Kk * Dd;   // one t2 partial (2M floats = 8 MB)

static __device__ __forceinline__ float b2f(bf16 v) { return __bfloat162float(v); }
static __device__ __forceinline__ bf16 f2b(float v) { return __float2bfloat16(v); }

// Fragment-order conventions (16x16x32 MFMA, K-step 32):
//   element (row, k): set = k>>5, q2 = (k>>3)&3, j = k&7
//   256-row group (tnbf, attn_bf, xb_bf): fi = (row>>4)*64 + q2*16 + (row&15); 1024 frags/step
//   64-row group (tbf/w1bf/w2bf):         fi = ((row&63)>>4)*64 + q2*16 + (row&15); 256 frags/step
//   32-row group (k_ffn rp tile):         fi = ((row&31)>>4)*64 + q2*16 + (row&15); 128 frags/set
// Reader identity: addr = set_base + (mtile_local*64 + lane)*8  (lane = q2*16 + row&15)
// LDS repack swizzle (bank-spread, involution): fi_sw = fi ^ ((fi>>3)&3)
//
// Config provenance (measured):
//   k_dots: R5/R10 pair-wise hw-64 + bounds(256,3), VGPR 80 -> 91-106 us session-dependent.
//     R11 hw-32 (occupancy 37%) REGRESSED (occupancy not binding). R6 superstep SPILLED.
//   k_gemm2: R8 hs-4 K-split partials, grid 2048.
//   k_ffn: fused ffn1+ffn2+LN_out (THIS ROUND: LN_out folded into k_ffn epilogue — block rg
//     owns its full 32x256 o2 tile; saves o2 8MB write + 8MB read + 1 dispatch).
//   k_tn: THIS ROUND also zeroes S (removes memset dispatch).
//   Plateau: 391.6-392.8 us over 3 structurally-different pipelines; mid-pipe is launch/drain bound.

// ---------------- k_tn: tnbf = l2norm(tgt) bf16 (+ S zeroing; grid == Bb*Kk) ----------------
__global__ __launch_bounds__(64) void k_tn(const float* __restrict__ tgt,
                                           bf16* __restrict__ tnbf,
                                           float* __restrict__ S) {
  int row = blockIdx.x;            // b*256 + slot
  int b = row >> 8, slot = row & 255;
  int lane = threadIdx.x;
  if (lane == 0) S[row] = 0.f;     // replaces hipMemsetAsync(S) (k_dots runs after)
  const float* src = tgt + (size_t)row * Dd + lane * 4;
  float v[4];
#pragma unroll
  for (int u = 0; u < 4; u++) v[u] = src[u];
  float ss = v[0] * v[0] + v[1] * v[1] + v[2] * v[2] + v[3] * v[3];
#pragma unroll
  for (int m = 32; m >= 1; m >>= 1) ss += __shfl_xor(ss, m, 64);
  float inv = 1.0f / fmaxf(sqrtf(ss), NORM_EPSf);
  bf16 o[4] __attribute__((aligned(8)));
#pragma unroll
  for (int u = 0; u < 4; u++) o[u] = f2b(v[u] * inv);
  int s = lane >> 3;
  int q2 = (lane >> 1) & 3;
  int jh = (lane & 1) * 4;
  size_t fi = (size_t)((slot >> 4) * 64 + q2 * 16 + (slot & 15));
  *(float2*)(tnbf + ((size_t)(b * 8 + s) * 1024 + fi) * 8 + jh) = *(float2*)o;
}

// ---------------- k_prew: w1 and w2 -> 64-row-group fragment order bf16 (merged launch) ----------------
__global__ __launch_bounds__(64) void k_prew(const float* __restrict__ w1,
                                             const float* __restrict__ w2,
                                             bf16* __restrict__ w1bf,
                                             bf16* __restrict__ w2bf) {
  int bidx = blockIdx.x;
  int lane = threadIdx.x;
  if (bidx < Ff) {
    int f = bidx;                  // 0..2047
    const float* src = w1 + (size_t)f * Dd + lane * 4;
    bf16 o[4] __attribute__((aligned(8)));
#pragma unroll
    for (int u = 0; u < 4; u++) o[u] = f2b(src[u]);
    int s = lane >> 3;
    int q2 = (lane >> 1) & 3;
    int jh = (lane & 1) * 4;
    size_t fi = (size_t)(((f & 63) >> 4) * 64 + q2 * 16 + (f & 15));
    *(float2*)(w1bf + ((size_t)((f >> 6) * 8 + s) * 256 + fi) * 8 + jh) = *(float2*)o;
  } else {
    int d = bidx - Ff;             // 0..255
    const float* src = w2 + (size_t)d * Ff + lane * 32;
    size_t gbase = (size_t)((d >> 6) * 64 + lane) * 256;
    int fbase = ((d & 63) >> 4) * 64 + (d & 15);
#pragma unroll
    for (int q2 = 0; q2 < 4; q2++) {
      float4 v0 = *(const float4*)(src + q2 * 8);
      float4 v1 = *(const float4*)(src + q2 * 8 + 4);
      bf16 o[8] __attribute__((aligned(16)));
      o[0] = f2b(v0.x); o[1] = f2b(v0.y); o[2] = f2b(v0.z); o[3] = f2b(v0.w);
      o[4] = f2b(v1.x); o[5] = f2b(v1.y); o[6] = f2b(v1.z); o[7] = f2b(v1.w);
      *(float4*)(w2bf + (gbase + fbase + q2 * 16) * 8) = *(float4*)o;
    }
  }
}

#define MFMA16(a, b, c) __builtin_amdgcn_mfma_f32_16x16x32_bf16(a, b, c, 0, 0, 0)

// ---------------- k_dots: softmax(slots) -> attn_bf (frag order), xb_bf (frag order), S ----------------
// R5 config: pair-wise double-buffered pipeline at 3 waves/SIMD, bounds(256,3), VGPR 80.
__global__ __launch_bounds__(256, 3) void k_dots(const bf16* __restrict__ tnbf,
                                                 const float* __restrict__ x,
                                                 bf16* __restrict__ xb_bf,
                                                 bf16* __restrict__ attn_bf,
                                                 float* __restrict__ S) {
  __shared__ __align__(16) char smem[23296];
  bf16* Bs = (bf16*)smem;                    // [4][2080]
  float* ssred = (float*)(smem + 16640);     // [64*17]
  float* nxl = (float*)(smem + 20992);       // [64]
  float* red = (float*)(smem + 21248);       // [512]
  int b = blockIdx.x >> 6;
  int hw0 = (blockIdx.x & 63) * 64;
  int tid = threadIdx.x;
  int wave = tid >> 6, lane = tid & 63;
  int quad = lane >> 4, nl = lane & 15;

  int dp = tid >> 4;           // 0..15
  int ch = tid & 15;           // 0..15
  int qb = dp >> 2;
  int jb = (dp & 3) * 2;

  f32x4 acc[4][4];
#pragma unroll
  for (int i = 0; i < 4; i++)
#pragma unroll
    for (int j = 0; j < 4; j++) acc[i][j] = (f32x4){0.f, 0.f, 0.f, 0.f};
  float ssp[4] = {0.f, 0.f, 0.f, 0.f};

  int spx = (hw0 >> 5) + (ch >> 3);
  int q2x = (ch >> 1) & 3;
  int jx = (ch & 1) * 4;

  const float* xbase = x + (size_t)((b << 8) + 2 * dp) * HWw + hw0 + ch * 4;
  float4 va4[2], vb4[2];
#pragma unroll
  for (int q = 0; q < 2; q++) {
    const float* xr = xbase + (size_t)(q * 32) * HWw;
    va4[q] = *(const float4*)xr;
    vb4[q] = *(const float4*)(xr + HWw);
  }
  short8 afp[4];
  {
    const bf16* ts0 = tnbf + (size_t)(b * 8) * 1024 * 8;
#pragma unroll
    for (int mt = 0; mt < 4; mt++)
      afp[mt] = *(const short8*)(ts0 + (size_t)(((wave << 2) + mt) * 64 + lane) * 8);
  }

#pragma unroll 1
  for (int p = 0; p < 4; p++) {
    bf16* bsb = Bs + (p & 1) * 2 * 2080;
    bf16 paS[2][4] __attribute__((aligned(8)));
    bf16 pbS[2][4] __attribute__((aligned(8)));
#pragma unroll
    for (int q = 0; q < 2; q++) {
      float vva[4] = {va4[q].x, va4[q].y, va4[q].z, va4[q].w};
      float vvb[4] = {vb4[q].x, vb4[q].y, vb4[q].z, vb4[q].w};
#pragma unroll
      for (int jj = 0; jj < 4; jj++) {
        ssp[jj] += vva[jj] * vva[jj] + vvb[jj] * vvb[jj];
        paS[q][jj] = f2b(vva[jj]);
        pbS[q][jj] = f2b(vvb[jj]);
      }
#pragma unroll
      for (int jj = 0; jj < 4; jj++) {
        int hwl = ch * 4 + jj;
        int nt = hwl >> 4;
        int li = (qb << 4) | (hwl & 15);
        union { bf16 h[2]; unsigned int u; } pk;
        pk.h[0] = paS[q][jj];
        pk.h[1] = pbS[q][jj];
        *(unsigned int*)&bsb[q * 2080 + nt * 520 + li * 8 + jb] = pk.u;
      }
    }
    __syncthreads();

#pragma unroll
    for (int q = 0; q < 2; q++) {
      int s = 2 * p + q;
      int d0r = s * 32 + 2 * dp;
      int fiA = (d0r >> 4) * 64 + q2x * 16 + (d0r & 15);
      size_t base = ((size_t)(b * 128) + spx) * 1024;
      *(float2*)(xb_bf + (base + fiA) * 8 + jx) = *(float2*)paS[q];
      *(float2*)(xb_bf + (base + fiA + 1) * 8 + jx) = *(float2*)pbS[q];
    }
    if (p < 3) {
#pragma unroll
      for (int q = 0; q < 2; q++) {
        const float* xr = xbase + (size_t)(((p + 1) * 2 + q) * 32) * HWw;
        va4[q] = *(const float4*)xr;
        vb4[q] = *(const float4*)(xr + HWw);
      }
    }
#pragma unroll
    for (int q = 0; q < 2; q++) {
      int s = 2 * p + q;
      short8 af[4];
#pragma unroll
      for (int mt = 0; mt < 4; mt++) af[mt] = afp[mt];
      if (s < 7) {
        const bf16* tsrc = tnbf + (size_t)(b * 8 + s + 1) * 1024 * 8;
#pragma unroll
        for (int mt = 0; mt < 4; mt++)
          afp[mt] = *(const short8*)(tsrc + (size_t)(((wave << 2) + mt) * 64 + lane) * 8);
      }
      short8 bfv[4];
#pragma unroll
      for (int nt = 0; nt < 4; nt++)
        bfv[nt] = *(const short8*)(bsb + q * 2080 + nt * 520 + lane * 8);
#pragma unroll
      for (int mt = 0; mt < 4; mt++)
#pragma unroll
        for (int nt = 0; nt < 4; nt++) acc[mt][nt] = MFMA16(af[mt], bfv[nt], acc[mt][nt]);
    }
  }

#pragma unroll
  for (int jj = 0; jj < 4; jj++) ssred[(ch * 4 + jj) * 17 + dp] = ssp[jj];
  __syncthreads();
  if (tid < 64) {
    float sum = 0.f;
#pragma unroll
    for (int i = 0; i < 16; i++) sum += ssred[tid * 17 + i];
    nxl[tid] = TEMP_INV / fmaxf(sqrtf(sum), NORM_EPSf);
  }
  __syncthreads();

  float sc[4];
#pragma unroll
  for (int nt = 0; nt < 4; nt++) sc[nt] = nxl[nt * 16 + nl];
#pragma unroll
  for (int mt = 0; mt < 4; mt++)
#pragma unroll
    for (int nt = 0; nt < 4; nt++)
#pragma unroll
      for (int r = 0; r < 4; r++) acc[mt][nt][r] *= sc[nt];

  float* red2 = red + 256;

  float pmax[4];
#pragma unroll
  for (int nt = 0; nt < 4; nt++) {
    float m = acc[0][nt][0];
#pragma unroll
    for (int mt = 0; mt < 4; mt++)
#pragma unroll
      for (int r = 0; r < 4; r++) m = fmaxf(m, acc[mt][nt][r]);
    m = fmaxf(m, __shfl_xor(m, 16, 64));
    m = fmaxf(m, __shfl_xor(m, 32, 64));
    pmax[nt] = m;
  }
  if (lane < 16) {
#pragma unroll
    for (int nt = 0; nt < 4; nt++) red[((wave << 2) + nt) * 16 + nl] = pmax[nt];
  }
  __syncthreads();
  float cmax[4];
#pragma unroll
  for (int nt = 0; nt < 4; nt++) {
    float m = red[nt * 16 + nl];
#pragma unroll
    for (int w2 = 1; w2 < 4; w2++) m = fmaxf(m, red[((w2 << 2) + nt) * 16 + nl]);
    cmax[nt] = m;
  }

  float psum[4];
#pragma unroll
  for (int nt = 0; nt < 4; nt++) {
    float s = 0.f;
#pragma unroll
    for (int mt = 0; mt < 4; mt++)
#pragma unroll
      for (int r = 0; r < 4; r++) {
        float e = __expf(acc[mt][nt][r] - cmax[nt]);
        acc[mt][nt][r] = e;
        s += e;
      }
    s += __shfl_xor(s, 16, 64);
    s += __shfl_xor(s, 32, 64);
    psum[nt] = s;
  }
  if (lane < 16) {
#pragma unroll
    for (int nt = 0; nt < 4; nt++) red2[((wave << 2) + nt) * 16 + nl] = psum[nt];
  }
  __syncthreads();
  float ci[4];
#pragma unroll
  for (int nt = 0; nt < 4; nt++) {
    float s = 0.f;
#pragma unroll
    for (int w2 = 0; w2 < 4; w2++) s += red2[((w2 << 2) + nt) * 16 + nl];
    ci[nt] = 1.0f / s;
  }

#pragma unroll
  for (int mt = 0; mt < 4; mt++) {
    int slotg = (b << 8) + (wave << 6) + (mt << 4) + (quad << 2);
#pragma unroll
    for (int r = 0; r < 4; r++) {
      float rs = 0.f;
#pragma unroll
      for (int nt = 0; nt < 4; nt++) {
        bf16 hb = f2b(acc[mt][nt][r] * ci[nt] + EPSf);
        float q = b2f(hb);
        acc[mt][nt][r] = q;
        rs += q;
      }
      rs += __shfl_xor(rs, 1, 64);
      rs += __shfl_xor(rs, 2, 64);
      rs += __shfl_xor(rs, 4, 64);
      rs += __shfl_xor(rs, 8, 64);
      if (nl == 0) atomicAdd(&S[slotg + r], rs);
    }
  }

  __syncthreads();
  bf16* rp = (bf16*)smem;
  int jat = nl & 7;
#pragma unroll
  for (int h = 0; h < 2; h++) {
#pragma unroll
    for (int mt = 0; mt < 4; mt++) {
      int fi0 = ((wave << 2) + mt) * 64 + (quad << 2);
#pragma unroll
      for (int ntl = 0; ntl < 2; ntl++) {
        int nt = (h << 1) + ntl;
        int q2p = (ntl << 1) + (nl >> 3);
#pragma unroll
        for (int r = 0; r < 4; r++) {
          int fi = fi0 + q2p * 16 + r;
          int fisw = fi ^ ((fi >> 3) & 3);
          rp[fisw * 8 + jat] = f2b(acc[mt][nt][r]);
        }
      }
    }
    __syncthreads();
    size_t gbase = ((size_t)(b * 128) + (hw0 >> 5) + h) * 1024 * 8;
#pragma unroll
    for (int u = 0; u < 4; u++) {
      int fl = u * 256 + tid;
      int fg = fl ^ ((fl >> 3) & 3);
      short8 vv = *(const short8*)(rp + (size_t)fl * 8);
      *(short8*)(attn_bf + gbase + (size_t)fg * 8) = vv;
    }
    if (h == 0) __syncthreads();
  }
}

// ---------------- GEMM2 (MFMA, zero-LDS, hs-4 K-split -> 4 partial buffers, NO atomics) ----------------
__global__ __launch_bounds__(256) void k_gemm2(const bf16* __restrict__ attn_bf,
                                               const bf16* __restrict__ xb_bf,
                                               float* __restrict__ t2p) {
  int n = blockIdx.x;
  int b = n & 31;
  int r2 = n >> 5;                 // 0..63
  int kp = r2 & 3;
  int dgrp = (r2 >> 2) & 3;
  int hs = r2 >> 4;
  int tid = threadIdx.x;
  int wave = tid >> 6, lane = tid & 63;
  int wr = wave >> 1, wc = wave & 1;

  f32x4 acc[2][2];
#pragma unroll
  for (int i = 0; i < 2; i++)
#pragma unroll
    for (int j = 0; j < 2; j++) acc[i][j] = (f32x4){0.f, 0.f, 0.f, 0.f};

  const bf16* Abase = attn_bf + ((size_t)(b * 128 + hs * 32) * 1024 + (size_t)(kp * 4 + wr * 2) * 64) * 8;
  const bf16* Bbase = xb_bf + ((size_t)(b * 128 + hs * 32) * 1024 + (size_t)(dgrp * 4 + wc * 2) * 64) * 8;
#pragma unroll 4
  for (int st = 0; st < 32; st++) {
    const bf16* Ap = Abase + (size_t)st * 1024 * 8;
    const bf16* Bp = Bbase + (size_t)st * 1024 * 8;
    short8 a0 = *(const short8*)(Ap + (size_t)lane * 8);
    short8 a1 = *(const short8*)(Ap + (size_t)(64 + lane) * 8);
    short8 b0 = *(const short8*)(Bp + (size_t)lane * 8);
    short8 b1 = *(const short8*)(Bp + (size_t)(64 + lane) * 8);
    acc[0][0] = MFMA16(a0, b0, acc[0][0]);
    acc[0][1] = MFMA16(a0, b1, acc[0][1]);
    acc[1][0] = MFMA16(a1, b0, acc[1][0]);
    acc[1][1] = MFMA16(a1, b1, acc[1][1]);
  }
  float* dst = t2p + (size_t)hs * PKD;
  int quad = lane >> 4, nl = lane & 15;
#pragma unroll
  for (int i = 0; i < 2; i++)
#pragma unroll
    for (int r = 0; r < 4; r++) {
      int row = (b << 8) + kp * 64 + wr * 32 + i * 16 + quad * 4 + r;
#pragma unroll
      for (int j = 0; j < 2; j++) {
        int col = dgrp * 64 + wc * 32 + j * 16 + nl;
        dst[(size_t)row * Dd + col] = acc[i][j][r];
      }
    }
}

// ---------------- LN_pre: t = LN(sum(t2 partials)/S + tgt); also tbf (64-row-group frag order) ----------------
__global__ __launch_bounds__(64) void k_ln_pre(const float* __restrict__ t2p,
                                               const float* __restrict__ S,
                                               const float* __restrict__ tgt,
                                               const float* __restrict__ g,
                                               const float* __restrict__ be,
                                               float* __restrict__ t,
                                               bf16* __restrict__ tbf) {
  int row = blockIdx.x;
  int lane = threadIdx.x;
  float sInv = 1.0f / S[row];
  size_t off = (size_t)row * Dd + lane * 4;
  float4 a0 = *(const float4*)(t2p + off);
  float4 a1 = *(const float4*)(t2p + PKD + off);
  float4 a2 = *(const float4*)(t2p + 2 * PKD + off);
  float4 a3 = *(const float4*)(t2p + 3 * PKD + off);
  const float* pt = tgt + off;
  float v[4];
  v[0] = (a0.x + a1.x + a2.x + a3.x) * sInv + pt[0];
  v[1] = (a0.y + a1.y + a2.y + a3.y) * sInv + pt[1];
  v[2] = (a0.z + a1.z + a2.z + a3.z) * sInv + pt[2];
  v[3] = (a0.w + a1.w + a2.w + a3.w) * sInv + pt[3];
  float s1 = v[0] + v[1] + v[2] + v[3];
  float s2 = v[0] * v[0] + v[1] * v[1] + v[2] * v[2] + v[3] * v[3];
#pragma unroll
  for (int m = 32; m >= 1; m >>= 1) {
    s1 += __shfl_xor(s1, m, 64);
    s2 += __shfl_xor(s2, m, 64);
  }
  float mu = s1 * (1.0f / 256.0f);
  float var = s2 * (1.0f / 256.0f) - mu * mu;
  float rs = rsqrtf(fmaxf(var, 0.f) + LN_EPSf);
  float* po = t + (size_t)row * Dd + lane * 4;
  bf16 o[4] __attribute__((aligned(8)));
#pragma unroll
  for (int u = 0; u < 4; u++) {
    float val = (v[u] - mu) * rs * g[lane * 4 + u] + be[lane * 4 + u];
    po[u] = val;
    o[u] = f2b(val);
  }
  int s = lane >> 3;
  int q2 = (lane >> 1) & 3;
  int jh = (lane & 1) * 4;
  size_t fi = (size_t)(((row & 63) >> 4) * 64 + q2 * 16 + (row & 15));
  *(float2*)(tbf + ((size_t)((row >> 6) * 8 + s) * 256 + fi) * 8 + jh) = *(float2*)o;
}

// ---------------- k_ffn: FUSED FFN + LN_out. out = LN(relu(t@w1^T+b1)@w2^T + b2 + t) ----------------
// grid 256 (rg = 32-row group), 512 threads (8 waves). c-loop identical to R10-proven k_ffn.
// Epilogue: block rg owns the full 32x256 o2 tile -> stage in LDS (32 x 264-pitch f32, aliases
// dead rp), wave w handles rows 4w..4w+3 (lane = one float4/row), full-wave shfl LN reduction,
// coalesced float4 out write. o2 never touches HBM.
__global__ __launch_bounds__(512, 2) void k_ffn(const bf16* __restrict__ tbf,
                                                const bf16* __restrict__ w1bf,
                                                const float* __restrict__ b1,
                                                const bf16* __restrict__ w2bf,
                                                const float* __restrict__ b2v,
                                                const float* __restrict__ t,
                                                const float* __restrict__ g3,
                                                const float* __restrict__ be3,
                                                float* __restrict__ out) {
  __shared__ __align__(16) char smem[33792];          // rp (8 KB) phase 1; vt (33792 B) phase 2
  bf16* rp = (bf16*)smem;                             // [2][2048]
  float* vt = (float*)smem;                           // [32][264] f32
  int rg = blockIdx.x;             // 0..255 (rows rg*32 .. +31)
  int tid = threadIdx.x;
  int wave = tid >> 6, lane = tid & 63;
  int quad = lane >> 4, nl = lane & 15;
  int mh = wave >> 2, fq = wave & 3;     // GEMM1 role
  int gg = rg >> 1, half = rg & 1;       // tbf 64-row group, half

  short8 af1[8];
  {
    const bf16* Ab = tbf + ((size_t)(gg * 8) * 256 + (size_t)((half * 2 + mh) * 64 + lane)) * 8;
#pragma unroll
    for (int s = 0; s < 8; s++) af1[s] = *(const short8*)(Ab + (size_t)s * 2048);
  }

  f32x4 acc2[2][2];
#pragma unroll
  for (int i = 0; i < 2; i++)
#pragma unroll
    for (int j = 0; j < 2; j++) acc2[i][j] = (f32x4){0.f, 0.f, 0.f, 0.f};

  int setw = fq >> 1;
  int q2w = (fq * 2 + (nl >> 3)) & 3;
  int jw = nl & 7;
  int dgrp2 = wave >> 1;
  int ntp0 = (wave & 1) * 2;

  auto G1 = [&](int cn) {
    f32x4 a1a = (f32x4){0.f, 0.f, 0.f, 0.f};
    f32x4 a1b = (f32x4){0.f, 0.f, 0.f, 0.f};
    const bf16* Bb1 = w1bf + ((size_t)(cn * 8) * 256 + (size_t)(fq * 64 + lane)) * 8;
#pragma unroll
    for (int s = 0; s < 8; s += 2) {
      short8 bv0 = *(const short8*)(Bb1 + (size_t)s * 2048);
      short8 bv1 = *(const short8*)(Bb1 + (size_t)(s + 1) * 2048);
      a1a = MFMA16(af1[s], bv0, a1a);
      a1b = MFMA16(af1[s + 1], bv1, a1b);
    }
    float bias = b1[cn * 64 + fq * 16 + nl];
    bf16* rpw = rp + (cn & 1) * 2048;
#pragma unroll
    for (int r = 0; r < 4; r++) {
      float hv = fmaxf(a1a[r] + a1b[r] + bias, 0.f);
      int fi = mh * 64 + q2w * 16 + quad * 4 + r;
      int fisw = fi ^ ((fi >> 3) & 3);
      rpw[(setw * 128 + fisw) * 8 + jw] = f2b(hv);
    }
  };

  G1(0);
  __syncthreads();

#pragma unroll 1
  for (int c = 0; c < 32; c++) {
    if (c < 31) G1(c + 1);
    const bf16* rpr = rp + (c & 1) * 2048;
#pragma unroll
    for (int ks = 0; ks < 2; ks++) {
      short8 a2[2];
#pragma unroll
      for (int mi = 0; mi < 2; mi++) {
        int fi = mi * 64 + lane;
        int fisw = fi ^ ((fi >> 3) & 3);
        a2[mi] = *(const short8*)(rpr + (ks * 128 + fisw) * 8);
      }
      int sg = c * 2 + ks;
#pragma unroll
      for (int nt = 0; nt < 2; nt++) {
        short8 b2 = *(const short8*)(w2bf + ((size_t)(dgrp2 * 64 + sg) * 256 + (size_t)((ntp0 + nt) * 64 + lane)) * 8);
        acc2[0][nt] = MFMA16(a2[0], b2, acc2[0][nt]);
        acc2[1][nt] = MFMA16(a2[1], b2, acc2[1][nt]);
      }
    }
    __syncthreads();   // also fences rp before vt overwrite in the epilogue
  }

  // ---- epilogue pass A: stage o2 tile into vt (rp is dead past the last barrier) ----
#pragma unroll
  for (int mi = 0; mi < 2; mi++)
#pragma unroll
    for (int r = 0; r < 4; r++) {
      int lrow = mi * 16 + quad * 4 + r;
#pragma unroll
      for (int nt = 0; nt < 2; nt++) {
        int col = wave * 32 + nt * 16 + nl;
        vt[lrow * 264 + col] = acc2[mi][nt][r];
      }
    }
  __syncthreads();

  // ---- epilogue pass B: per-row LN; wave w owns rows 4w..4w+3, lane = one float4 per row ----
  const float4 bv = *(const float4*)(b2v + lane * 4);
  const float4 gv = *(const float4*)(g3 + lane * 4);
  const float4 ev = *(const float4*)(be3 + lane * 4);
#pragma unroll
  for (int rr = 0; rr < 4; rr++) {
    int lrow = wave * 4 + rr;
    int grow = rg * 32 + lrow;
    float4 a = *(const float4*)(vt + lrow * 264 + lane * 4);
    float4 tv = *(const float4*)(t + (size_t)grow * Dd + lane * 4);
    float v0 = a.x + bv.x + tv.x;
    float v1 = a.y + bv.y + tv.y;
    float v2 = a.z + bv.z + tv.z;
    float v3 = a.w + bv.w + tv.w;
    float s1 = v0 + v1 + v2 + v3;
    float s2 = v0 * v0 + v1 * v1 + v2 * v2 + v3 * v3;
#pragma unroll
    for (int m = 32; m >= 1; m >>= 1) {
      s1 += __shfl_xor(s1, m, 64);
      s2 += __shfl_xor(s2, m, 64);
    }
    float mu = s1 * (1.0f / 256.0f);
    float var = s2 * (1.0f / 256.0f) - mu * mu;
    float rsv = rsqrtf(fmaxf(var, 0.f) + LN_EPSf);
    float4 o;
    o.x = (v0 - mu) * rsv * gv.x + ev.x;
    o.y = (v1 - mu) * rsv * gv.y + ev.y;
    o.z = (v2 - mu) * rsv * gv.z + ev.z;
    o.w = (v3 - mu) * rsv * gv.w + ev.w;
    *(float4*)(out + (size_t)grow * Dd + lane * 4) = o;
  }
}

extern "C" void kernel_launch(void* const* d_in, const int* in_sizes, int n_in,
                              void* d_out, int out_size, void* d_ws, size_t ws_size,
                              hipStream_t stream) {
  const float* x = (const float*)d_in[0];
  const float* tgt = (const float*)d_in[1];
  const float* w1 = (const float*)d_in[2];
  const float* b1 = (const float*)d_in[3];
  const float* w2 = (const float*)d_in[4];
  const float* b2v = (const float*)d_in[5];
  const float* g2 = (const float*)d_in[6];
  const float* be2 = (const float*)d_in[7];
  const float* g3 = (const float*)d_in[8];
  const float* be3 = (const float*)d_in[9];
  float* out = (float*)d_out;

  // Aliasing:
  //   tbf -> tnbf (dead after k_dots)
  //   w1bf/w2bf carved from attn_bf head (attn dead after gemm2; prew runs after gemm2)
  //   t2 partials (4x8MB = 32MB) -> h1reg region (read by ln_pre)
  //   o2 eliminated (LN fused into k_ffn)
  char* w = (char*)d_ws;
  bf16* tnbf = (bf16*)w;     w += (size_t)Bb * Kk * Dd * 2;   // 4 MB
  float* S = (float*)w;      w += (size_t)Bb * Kk * 4;        // 32 KB
  float* t = (float*)w;      w += (size_t)Bb * Kk * Dd * 4;   // 8 MB
  bf16* attn_bf = (bf16*)w;  w += (size_t)Bb * HWw * Kk * 2;  // 64 MB
  bf16* h1reg = (bf16*)w;    w += (size_t)Bb * Kk * Ff * 2;   // 32 MB (t2p lives here)
  bf16* xb_bf = (bf16*)w;    w += (size_t)Bb * Dd * HWw * 2;  // 64 MB

  bf16* tbf = tnbf;                        // 4 MB alias
  bf16* w1bf = attn_bf;                    // 1 MB carve
  bf16* w2bf = attn_bf + (size_t)Ff * Dd;  // 1 MB carve
  float* t2p = (float*)h1reg;              // 32 MB alias (4 partials)

  k_tn<<<Bb * Kk, 64, 0, stream>>>(tgt, tnbf, S);
  k_dots<<<Bb * (HWw / 64), 256, 0, stream>>>(tnbf, x, xb_bf, attn_bf, S);
  k_gemm2<<<2048, 256, 0, stream>>>(attn_bf, xb_bf, t2p);
  k_prew<<<Ff + Dd, 64, 0, stream>>>(w1, w2, w1bf, w2bf);
  k_ln_pre<<<Bb * Kk, 64, 0, stream>>>(t2p, S, tgt, g2, be2, t, tbf);
  k_ffn<<<(Bb * Kk) / 32, 512, 0, stream>>>(tbf, w1bf, b1, w2bf, b2v, t, g3, be3, out);
}